// Round 8
// baseline (635.036 us; speedup 1.0000x reference)
//
#include <hip/hip_runtime.h>

#define E_ 8
#define D_ 1024
#define F_ 4096
#define T_ 8192

typedef unsigned short u16;
typedef short bf16x8 __attribute__((ext_vector_type(8)));
typedef float f32x4 __attribute__((ext_vector_type(4)));
typedef unsigned short u16x8 __attribute__((ext_vector_type(8)));
typedef unsigned int u32x4 __attribute__((ext_vector_type(4)));

__device__ __forceinline__ u16 f2bf(float f) {
    unsigned u = __builtin_bit_cast(unsigned, f);
    u += 0x7fffu + ((u >> 16) & 1u);   // RNE
    return (u16)(u >> 16);
}

// v_cvt_pk_bf16_f32: lo = bf16(a), hi = bf16(b), RNE
__device__ __forceinline__ unsigned cvtpk(float a, float b) {
    unsigned d;
    asm("v_cvt_pk_bf16_f32 %0, %1, %2" : "=v"(d) : "v"(a), "v"(b));
    return d;
}

// gelu_tanh(x) = x * sigmoid(2*k0*(x + k1 x^3)); exp2+rcp, ~10 VALU
__device__ __forceinline__ float gelu_fast(float x) {
    const float a = -2.885390082f * 0.7978845608028654f;  // -2*log2(e)*k0
    const float b = a * 0.044715f;
    float u = x * x;
    float p = x * __builtin_fmaf(b, u, a);
    float e = exp2f(p);
    return x * __builtin_amdgcn_rcpf(1.0f + e);
}

// async global->LDS, 16B per lane; lds base must be wave-uniform
__device__ __forceinline__ void async16(const void* g, void* l) {
    __builtin_amdgcn_global_load_lds(
        (const __attribute__((address_space(1))) unsigned int*)g,
        (__attribute__((address_space(3))) unsigned int*)l, 16, 0, 0);
}

// ---------------- elementwise fp32 -> bf16 (X) ----------------
__global__ void cvt_x(const float* __restrict__ in, u16* __restrict__ out) {
    int i = blockIdx.x * 256 + threadIdx.x;     // one thread = 8 elements
    const float4* in4 = (const float4*)in;
    float4 a = in4[2 * i], b = in4[2 * i + 1];
    u16x8 o;
    o[0] = f2bf(a.x); o[1] = f2bf(a.y); o[2] = f2bf(a.z); o[3] = f2bf(a.w);
    o[4] = f2bf(b.x); o[5] = f2bf(b.y); o[6] = f2bf(b.z); o[7] = f2bf(b.w);
    *(u16x8*)(out + (size_t)i * 8) = o;
}

// ======================================================================
// 2-phase pipelined bf16 GEMM with NATIVE-layout fp32 weights:
//   C[M][N] = A_bf16[M][K] * W_fp32[K][N] + bias
// BM=256, BK=64 (two kh slabs), 8 waves (4m x 2n), dbuf LDS.
// A staged via global_load_lds (bf16, k-contiguous, swizzled-source T2).
// B staged via narrow loads + cvt_pk + ds_write_b128:
//   thread unit = 1n x 8k fp32: 8x b32 loads (wave instr = 256B contiguous
//   k-row of W), 4 cvt_pk, one b128 write at [n][32k] swizzled slab.
//   Write wave-instr = 64 consecutive n -> quarter-wave 2 lanes/bank-slot
//   (free), mirroring the measured-0-conflict frag-read pattern.
// Pipeline: kh0(c+1) loaded P1(c-1)/written P0(c); kh1(c+1) loaded P0(c)/
//   written P1(c) -> B(c+1) complete before the c->c+1 boundary barrier.
// vmcnt ledger (issue order: B-loads then A-stage): steady vmcnt(2) each
//   phase end retires this phase's B-loads + prior A-stage, leaves the
//   newest A-stage (2). lgkm: entry guard = reads(12/8)+writes(2/1); mid
//   guard = MFR+NH.
// EPI==1: C = bf16(gelu(acc+bias)) ; EPI==0: C = f32 acc+bias
// ======================================================================
template <int BN, int EPI, int NM, int NN>
__global__ __launch_bounds__(512, 2) void gemm2pw(
    const u16* __restrict__ A,      // [E][Mpe][K] bf16
    const float* __restrict__ W,    // [E][K][N]   fp32 (native)
    const float* __restrict__ bias, // [E][N]
    void* __restrict__ Cv,          // [E][Mpe][N]
    int Mpe, int N, int K) {
    constexpr int BM  = 256;
    constexpr int LA  = 2;            // A kh-slab gload insts per thread
    constexpr int MFR = 4;            // wave tile 64 rows (4m x 2n grid)
    constexpr int NFR = BN / 32;      // 8 (BN=256) or 4 (BN=128)
    constexpr int NH  = NFR / 2;      // n-frags per sub-cluster
    constexpr int UNITS = BN / 128;   // B units per phase per thread (2/1)
    constexpr int AELEM = 4 * BM * 32;
    constexpr int RD  = MFR + 2 * NH; // ds_reads per full phase (12 or 8)
    constexpr int ENTRY = RD + UNITS; // entry guard (14 or 9)
    constexpr int MID = MFR + NH;     // mid guard (8 or 6)
    __shared__ u16 lds[AELEM + 4 * BN * 32];

    const int tid = threadIdx.x;
    const int w = tid >> 6, lane = tid & 63;
    const int lr = lane & 15, lg = lane >> 4;
    const int wm = w >> 1, wn = w & 1;

    // ---- 1D grid -> bijective XCD chunking -> (e, n, m) m-innermost ----
    constexpr int NWG = E_ * NM * NN;
    constexpr int PER = NWG / 8;
    const int bid = blockIdx.x;
    const int logical = (bid & 7) * PER + (bid >> 3);
    const int e   = logical / (NM * NN);
    const int rem = logical % (NM * NN);
    const int bn  = rem / NM;
    const int bm  = rem % NM;

    A    += (size_t)e * Mpe * K;
    W    += (size_t)e * K * N;
    bias += (size_t)e * N;
    const int n0 = bn * BN;
    const int m0 = bm * BM;
    const int NT = K >> 6;

    // ---- A: per-thread global byte pointers, chunk pre-swizzled (T2) ----
    const char* gA[LA];
    {
        int kch = (lane & 3) ^ ((lane >> 3) & 3);   // inverse of read swizzle
#pragma unroll
        for (int i = 0; i < LA; ++i) {
            int row = i * 128 + w * 16 + (lane >> 2);
            gA[i] = (const char*)(A + (size_t)(m0 + row) * K + kch * 8);
        }
    }
    char* ldsc = (char*)lds;

    auto stageA = [&](int t, int h) {
        size_t goff = (size_t)t * 128 + (size_t)h * 64;   // bytes along K
        unsigned dst = (unsigned)((((t & 1) * 2 + h) * (BM * 64)) + w * 1024);
#pragma unroll
        for (int i = 0; i < LA; ++i)
            async16(gA[i] + goff, ldsc + dst + i * 8192);
    };

    // ---- B: narrow-load + repack staging ----
    // thread owns n-rows: nl = NBLK*64 + lane; octets OCT0..OCT0+UNITS-1
    const int NBLK = w & (BN / 64 - 1);
    const int OCT0 = (w / (BN / 64)) * UNITS;
    const int nl = NBLK * 64 + lane;
    const float* Wb = W + n0 + nl;            // + row*N walks k
    float fb[UNITS * 8];

    auto loadB = [&](int t, int h) {          // UNITS*8 b32 loads
#pragma unroll
        for (int u = 0; u < UNITS; ++u)
#pragma unroll
            for (int j = 0; j < 8; ++j) {
                int row = t * 64 + h * 32 + (OCT0 + u) * 8 + j;
                fb[u * 8 + j] = Wb[(size_t)row * N];
            }
    };
    // swizzled byte offset of this thread's b128 slot within a B slab
    const int bwswz = ((nl >> 1) & 3);
    auto writeB = [&](int t, int h) {         // UNITS ds_write_b128
        unsigned base = (unsigned)(AELEM * 2 + (((t & 1) * 2 + h) * (BN * 64)));
#pragma unroll
        for (int u = 0; u < UNITS; ++u) {
            u32x4 v;
            v[0] = cvtpk(fb[u * 8 + 0], fb[u * 8 + 1]);
            v[1] = cvtpk(fb[u * 8 + 2], fb[u * 8 + 3]);
            v[2] = cvtpk(fb[u * 8 + 4], fb[u * 8 + 5]);
            v[3] = cvtpk(fb[u * 8 + 6], fb[u * 8 + 7]);
            *(u32x4*)(ldsc + base + nl * 64 + (((OCT0 + u) ^ bwswz) << 4)) = v;
        }
    };

    f32x4 acc[MFR][NFR];
    const f32x4 zero = {0.f, 0.f, 0.f, 0.f};
#pragma unroll
    for (int i = 0; i < MFR; ++i)
#pragma unroll
        for (int j = 0; j < NFR; ++j) acc[i][j] = zero;

    const u16* SBb = lds + AELEM;
    const int arow = wm * 64 + lr;
    const int nbase = wn * (BN / 2) + lr;
    const int axor = (lg ^ ((arow >> 1) & 3)) * 8;
    const int bxor = (lg ^ ((nbase >> 1) & 3)) * 8;

    bf16x8 aC[MFR], aN[MFR], bloA[NH], bloB[NH], bhi[NH];

    // ---- prologue: B(0) via reg path; A(0) both kh + A(1,kh0); B(1,kh0) ----
    loadB(0, 0);
    asm volatile("s_waitcnt vmcnt(0)" ::: "memory");
    writeB(0, 0);
    loadB(0, 1);
    asm volatile("s_waitcnt vmcnt(0)" ::: "memory");
    writeB(0, 1);
    loadB(1, 0);                               // written at P0(c=0)
    stageA(0, 0); stageA(0, 1); stageA(1, 0);
    asm volatile("s_waitcnt vmcnt(0)" ::: "memory");
    __builtin_amdgcn_s_barrier();
    __builtin_amdgcn_sched_barrier(0);
#pragma unroll
    for (int i = 0; i < MFR; ++i)
        aC[i] = *(const bf16x8*)(lds + (arow + i * 16) * 32 + axor);
#pragma unroll
    for (int j = 0; j < NH; ++j)
        bloA[j] = *(const bf16x8*)(SBb + (nbase + j * 16) * 32 + bxor);
    __builtin_amdgcn_sched_barrier(0);

#define MFMA_SUB(AARR, BARR, J0)                                              \
    __builtin_amdgcn_s_setprio(1);                                            \
    _Pragma("unroll")                                                         \
    for (int i = 0; i < MFR; ++i) {                                           \
        _Pragma("unroll")                                                     \
        for (int j = 0; j < NH; ++j)                                          \
            acc[i][(J0) + j] = __builtin_amdgcn_mfma_f32_16x16x32_bf16(       \
                AARR[i], BARR[j], acc[i][(J0) + j], 0, 0, 0);                 \
    }                                                                         \
    __builtin_amdgcn_s_setprio(0);

    for (int c = 0; c < NT; ++c) {
        const int bb = c & 1;
        const u16* SA1 = lds + (bb * 2 + 1) * (BM * 32);
        const u16* SB0 = SBb + (bb * 2 + 0) * (BN * 32);
        const u16* SB1 = SBb + (bb * 2 + 1) * (BN * 32);
        const u16* SA0n = lds + ((bb ^ 1) * 2) * (BM * 32);
        const u16* SB0n = SBb + ((bb ^ 1) * 2) * (BN * 32);
        const bool stg1 = (c + 1 < NT);
        const bool stg2 = (c + 2 < NT);

        // ================= P0: computes kh0 of tile c =================
        if (stg1) { writeB(c + 1, 0); loadB(c + 1, 1); }
#pragma unroll
        for (int j = 0; j < NH; ++j)
            bhi[j] = *(const bf16x8*)(SB0 + (nbase + (NH + j) * 16) * 32 + bxor);
#pragma unroll
        for (int i = 0; i < MFR; ++i)
            aN[i] = *(const bf16x8*)(SA1 + (arow + i * 16) * 32 + axor);
#pragma unroll
        for (int j = 0; j < NH; ++j)
            bloB[j] = *(const bf16x8*)(SB1 + (nbase + j * 16) * 32 + bxor);
        if (stg1) stageA(c + 1, 1);
        __builtin_amdgcn_sched_barrier(0);
        if (stg1) asm volatile("s_waitcnt lgkmcnt(%0)" :: "i"(ENTRY) : "memory");
        else      asm volatile("s_waitcnt lgkmcnt(%0)" :: "i"(RD) : "memory");
        __builtin_amdgcn_sched_barrier(0);
        MFMA_SUB(aC, bloA, 0);
        __builtin_amdgcn_sched_barrier(0);
        asm volatile("s_waitcnt lgkmcnt(%0)" :: "i"(MID) : "memory");
        __builtin_amdgcn_sched_barrier(0);
        MFMA_SUB(aC, bhi, NH);
        __builtin_amdgcn_sched_barrier(0);
        if (stg1) asm volatile("s_waitcnt vmcnt(2)" ::: "memory");
        else      asm volatile("s_waitcnt vmcnt(0)" ::: "memory");
        __builtin_amdgcn_s_barrier();
        __builtin_amdgcn_sched_barrier(0);

        // ================= P1: computes kh1 of tile c =================
        if (stg1) writeB(c + 1, 1);
        if (stg2) loadB(c + 2, 0);
#pragma unroll
        for (int j = 0; j < NH; ++j)
            bhi[j] = *(const bf16x8*)(SB1 + (nbase + (NH + j) * 16) * 32 + bxor);
        if (stg1) {
#pragma unroll
            for (int i = 0; i < MFR; ++i)
                aC[i] = *(const bf16x8*)(SA0n + (arow + i * 16) * 32 + axor);
#pragma unroll
            for (int j = 0; j < NH; ++j)
                bloA[j] = *(const bf16x8*)(SB0n + (nbase + j * 16) * 32 + bxor);
        }
        if (stg2) stageA(c + 2, 0);
        __builtin_amdgcn_sched_barrier(0);
        if (stg1) asm volatile("s_waitcnt lgkmcnt(%0)" :: "i"(ENTRY) : "memory");
        else      asm volatile("s_waitcnt lgkmcnt(%0)" :: "i"(NH) : "memory");
        __builtin_amdgcn_sched_barrier(0);
        MFMA_SUB(aN, bloB, 0);
        __builtin_amdgcn_sched_barrier(0);
        if (stg1) asm volatile("s_waitcnt lgkmcnt(%0)" :: "i"(MID) : "memory");
        else      asm volatile("s_waitcnt lgkmcnt(0)" ::: "memory");
        __builtin_amdgcn_sched_barrier(0);
        MFMA_SUB(aN, bhi, NH);
        __builtin_amdgcn_sched_barrier(0);
        if (stg2) asm volatile("s_waitcnt vmcnt(2)" ::: "memory");
        else      asm volatile("s_waitcnt vmcnt(0)" ::: "memory");
        __builtin_amdgcn_s_barrier();
        __builtin_amdgcn_sched_barrier(0);
    }
#undef MFMA_SUB

    // ---- epilogue: C/D layout col=lane&15, row=(lane>>4)*4+t ----
    const int mb = m0 + wm * 64, nb = n0 + wn * (BN / 2);
    if constexpr (EPI == 1) {
        u16* C = (u16*)Cv + (size_t)e * Mpe * N;
#pragma unroll
        for (int i = 0; i < MFR; ++i) {
#pragma unroll
            for (int j = 0; j < NFR; ++j) {
                int col = nb + j * 16 + lr;
                float bv = bias[col];
                int row = mb + i * 16 + lg * 4;
#pragma unroll
                for (int t = 0; t < 4; ++t) {
                    float v = acc[i][j][t] + bv;
                    C[(size_t)(row + t) * N + col] = f2bf(gelu_fast(v));
                }
            }
        }
    } else {
        float* C = (float*)Cv + (size_t)e * Mpe * N;
#pragma unroll
        for (int i = 0; i < MFR; ++i) {
#pragma unroll
            for (int j = 0; j < NFR; ++j) {
                int col = nb + j * 16 + lr;
                float bv = bias[col];
                int row = mb + i * 16 + lg * 4;
#pragma unroll
                for (int t = 0; t < 4; ++t)
                    C[(size_t)(row + t) * N + col] = acc[i][j][t] + bv;
            }
        }
    }
}

extern "C" void kernel_launch(void* const* d_in, const int* in_sizes, int n_in,
                              void* d_out, int out_size, void* d_ws, size_t ws_size,
                              hipStream_t stream) {
    const float* X  = (const float*)d_in[0];
    // d_in[1] = expertFrequency (int64) — static equal split, unused
    const float* w1 = (const float*)d_in[2];
    const float* b1 = (const float*)d_in[3];
    const float* w2 = (const float*)d_in[4];
    const float* b2 = (const float*)d_in[5];
    float* out = (float*)d_out;

    // workspace layout (bytes): Xbf [T*D*2] | H [T*F*2]
    const size_t XBF_B = (size_t)T_ * D_ * 2;       // 16 MiB
    const size_t H_B   = (size_t)T_ * F_ * 2;       // 64 MiB
    if (ws_size < XBF_B + H_B) return;              // guard (80 MiB needed)

    char* ws = (char*)d_ws;
    u16* Xbf = (u16*)ws;
    u16* H   = (u16*)(ws + XBF_B);

    // 1. X fp32 -> bf16
    cvt_x<<<dim3((T_ * D_) / 8 / 256), dim3(256), 0, stream>>>(X, Xbf);
    // 2. H = gelu(X @ W1 + b1), bf16   (BM=256, BN=256; 512 wgs; W1 native)
    gemm2pw<256, 1, 4, 16><<<dim3(512), dim3(512), 0, stream>>>(
        Xbf, w1, b1, H, T_ / E_, F_, D_);
    // 3. out = H @ W2 + b2, fp32       (BM=256, BN=128; 256 wgs; W2 native)
    gemm2pw<128, 0, 4, 8><<<dim3(256), dim3(512), 0, stream>>>(
        H, w2, b2, out, T_ / E_, D_, F_);
}

// Round 9
// 435.015 us; speedup vs baseline: 1.4598x; 1.4598x over previous
//
#include <hip/hip_runtime.h>

#define E_ 8
#define D_ 1024
#define F_ 4096
#define T_ 8192

typedef unsigned short u16;
typedef short bf16x8 __attribute__((ext_vector_type(8)));
typedef float f32x4 __attribute__((ext_vector_type(4)));
typedef unsigned short u16x8 __attribute__((ext_vector_type(8)));
typedef unsigned int u32x4 __attribute__((ext_vector_type(4)));

__device__ __forceinline__ u16 f2bf(float f) {
    unsigned u = __builtin_bit_cast(unsigned, f);
    u += 0x7fffu + ((u >> 16) & 1u);   // RNE
    return (u16)(u >> 16);
}

// v_cvt_pk_bf16_f32: lo = bf16(a), hi = bf16(b), RNE
__device__ __forceinline__ unsigned cvtpk(float a, float b) {
    unsigned d;
    asm("v_cvt_pk_bf16_f32 %0, %1, %2" : "=v"(d) : "v"(a), "v"(b));
    return d;
}

// gelu_tanh(x) = x * sigmoid(2*k0*(x + k1 x^3)); exp2+rcp, ~10 VALU
__device__ __forceinline__ float gelu_fast(float x) {
    const float a = -2.885390082f * 0.7978845608028654f;  // -2*log2(e)*k0
    const float b = a * 0.044715f;
    float u = x * x;
    float p = x * __builtin_fmaf(b, u, a);
    float e = exp2f(p);
    return x * __builtin_amdgcn_rcpf(1.0f + e);
}

// async global->LDS, 16B per lane; lds base must be wave-uniform
__device__ __forceinline__ void async16(const void* g, void* l) {
    __builtin_amdgcn_global_load_lds(
        (const __attribute__((address_space(1))) unsigned int*)g,
        (__attribute__((address_space(3))) unsigned int*)l, 16, 0, 0);
}

// ---------------- elementwise fp32 -> bf16 (X) ----------------
__global__ void cvt_x(const float* __restrict__ in, u16* __restrict__ out) {
    int i = blockIdx.x * 256 + threadIdx.x;     // one thread = 8 elements
    const float4* in4 = (const float4*)in;
    float4 a = in4[2 * i], b = in4[2 * i + 1];
    u16x8 o;
    o[0] = f2bf(a.x); o[1] = f2bf(a.y); o[2] = f2bf(a.z); o[3] = f2bf(a.w);
    o[4] = f2bf(b.x); o[5] = f2bf(b.y); o[6] = f2bf(b.z); o[7] = f2bf(b.w);
    *(u16x8*)(out + (size_t)i * 8) = o;
}

// ======================================================================
// 2-phase pipelined bf16 GEMM, NATIVE fp32 [K][N] weights:
//   C[M][N] = A_bf16[M][K] * W_fp32[K][N] + bias
// BM=256, BK=64 (two kh slabs), 8 waves (4m x 2n), dbuf LDS.
// A: global_load_lds (bf16 k-contig, T2 pre-swizzled source).
// B: reg-staged (T14): float2/float loads (coalesced k-rows of W) ->
//    cvt_pk -> ds_write_b128 into the swizzled [n][32k] slab.
//    REGISTER DBUF fbA (kh0 slabs) / fbB (kh1 slabs), static names.
//    Depth: load@phase p -> write@p+1 (one full phase of latency cover).
// Ledger (per phase, issue order: [vmcnt(LA) writeB][ds reads][loadB]
// [stageA] ... [end vmcnt(LBI+LA)]):
//  - pre-write vmcnt(LA): drains PREV phase's B-loads (older than prev
//    stageA), never this phase's.
//  - end vmcnt(LBI+LA): retires everything through prev phase.
//  - entry lgkm = Wr+RD (prev reads done); mid lgkm = MFR+NH (bhi ready,
//    AND this phase's ds_writes published before the end barrier).
// EPI==1: C = bf16(gelu(acc+bias)) ; EPI==0: C = f32 acc+bias
// ======================================================================
template <int BN, int EPI, int NM, int NN>
__global__ __launch_bounds__(512, 2) void gemm2pw(
    const u16* __restrict__ A,      // [E][Mpe][K] bf16
    const float* __restrict__ W,    // [E][K][N]   fp32 (native)
    const float* __restrict__ bias, // [E][N]
    void* __restrict__ Cv,          // [E][Mpe][N]
    int Mpe, int N, int K) {
    constexpr int BM  = 256;
    constexpr int LA  = 2;            // A kh-slab gload insts per thread
    constexpr int MFR = 4;            // wave tile 64 rows (4m x 2n grid)
    constexpr int NFR = BN / 32;      // 8 (BN=256) or 4 (BN=128)
    constexpr int NH  = NFR / 2;      // n-frags per sub-cluster
    constexpr int NPT = BN / 128;     // n-rows per thread in B staging (2/1)
    constexpr int LBI = 8;            // B load insts per thread per phase
    constexpr int WR  = NPT;          // ds_write_b128 per thread per phase
    constexpr int AELEM = 4 * BM * 32;
    constexpr int RD  = MFR + 2 * NH; // ds_reads per full phase (12 or 8)
    constexpr int MID = MFR + NH;     // mid guard (8 or 6)
    constexpr int VEND = LBI + LA;    // steady end-of-phase vmcnt (10)
    __shared__ u16 lds[AELEM + 4 * BN * 32];

    const int tid = threadIdx.x;
    const int w = tid >> 6, lane = tid & 63;
    const int lr = lane & 15, lg = lane >> 4;
    const int wm = w >> 1, wn = w & 1;

    // ---- 1D grid -> bijective XCD chunking -> (e, n, m) m-innermost ----
    constexpr int NWG = E_ * NM * NN;
    constexpr int PER = NWG / 8;
    const int bid = blockIdx.x;
    const int logical = (bid & 7) * PER + (bid >> 3);
    const int e   = logical / (NM * NN);
    const int rem = logical % (NM * NN);
    const int bn  = rem / NM;
    const int bm  = rem % NM;

    A    += (size_t)e * Mpe * K;
    W    += (size_t)e * K * N;
    bias += (size_t)e * N;
    const int n0 = bn * BN;
    const int m0 = bm * BM;
    const int NT = K >> 6;

    // ---- A: per-thread global byte pointers, chunk pre-swizzled (T2) ----
    const char* gA[LA];
    {
        int kch = (lane & 3) ^ ((lane >> 3) & 3);   // inverse of read swizzle
#pragma unroll
        for (int i = 0; i < LA; ++i) {
            int row = i * 128 + w * 16 + (lane >> 2);
            gA[i] = (const char*)(A + (size_t)(m0 + row) * K + kch * 8);
        }
    }
    char* ldsc = (char*)lds;

    auto stageA = [&](int t, int h) {
        size_t goff = (size_t)t * 128 + (size_t)h * 64;   // bytes along K
        unsigned dst = (unsigned)((((t & 1) * 2 + h) * (BM * 64)) + w * 1024);
#pragma unroll
        for (int i = 0; i < LA; ++i)
            async16(gA[i] + goff, ldsc + dst + i * 8192);
    };

    // ---- B: reg staging maps ----
    const int p = (w & 1) * 64 + lane;        // 0..127
    const int o = w >> 1;                     // k-octet 0..3
    const float* WbT = W + n0 + NPT * p;      // + row*N walks k
    float fbA[8 * NPT], fbB[8 * NPT];

    auto loadB = [&](int t, int h, float* fb) {   // LBI=8 loads
#pragma unroll
        for (int j = 0; j < 8; ++j) {
            int r = t * 64 + h * 32 + o * 8 + j;
            if constexpr (NPT == 2) {
                float2 v = *(const float2*)(WbT + (size_t)r * N);
                fb[2 * j] = v.x; fb[2 * j + 1] = v.y;
            } else {
                fb[j] = WbT[(size_t)r * N];
            }
        }
    };
    auto writeB = [&](int t, int h, const float* fb) {   // WR b128 writes
        unsigned base = (unsigned)(AELEM * 2 + (((t & 1) * 2 + h) * (BN * 64)));
#pragma unroll
        for (int q = 0; q < NPT; ++q) {
            int n = NPT * p + q;
            int sw = (n >> 1) & 3;
            u32x4 v;
            v[0] = cvtpk(fb[NPT * 0 + q], fb[NPT * 1 + q]);
            v[1] = cvtpk(fb[NPT * 2 + q], fb[NPT * 3 + q]);
            v[2] = cvtpk(fb[NPT * 4 + q], fb[NPT * 5 + q]);
            v[3] = cvtpk(fb[NPT * 6 + q], fb[NPT * 7 + q]);
            *(u32x4*)(ldsc + base + n * 64 + ((o ^ sw) << 4)) = v;
        }
    };

    f32x4 acc[MFR][NFR];
    const f32x4 zero = {0.f, 0.f, 0.f, 0.f};
#pragma unroll
    for (int i = 0; i < MFR; ++i)
#pragma unroll
        for (int j = 0; j < NFR; ++j) acc[i][j] = zero;

    const u16* SBb = lds + AELEM;
    const int arow = wm * 64 + lr;
    const int nbase = wn * (BN / 2) + lr;
    const int axor = (lg ^ ((arow >> 1) & 3)) * 8;
    const int bxor = (lg ^ ((nbase >> 1) & 3)) * 8;

    bf16x8 aC[MFR], aN[MFR], bloA[NH], bloB[NH], bhi[NH];

    // ---- prologue (fully drained; one-time cost) ----
    loadB(0, 0, fbA); loadB(0, 1, fbB);
    stageA(0, 0); stageA(0, 1);
    if (NT > 1) stageA(1, 0);
    asm volatile("s_waitcnt vmcnt(0)" ::: "memory");
    writeB(0, 0, fbA); writeB(0, 1, fbB);
    if (NT > 1) loadB(1, 0, fbA);          // written at P0(c=0)
    asm volatile("s_waitcnt vmcnt(0)" ::: "memory");
    asm volatile("s_waitcnt lgkmcnt(0)" ::: "memory");
    __builtin_amdgcn_s_barrier();
    __builtin_amdgcn_sched_barrier(0);
#pragma unroll
    for (int i = 0; i < MFR; ++i)
        aC[i] = *(const bf16x8*)(lds + (arow + i * 16) * 32 + axor);
#pragma unroll
    for (int j = 0; j < NH; ++j)
        bloA[j] = *(const bf16x8*)(SBb + (nbase + j * 16) * 32 + bxor);
    __builtin_amdgcn_sched_barrier(0);

#define MFMA_SUB(AARR, BARR, J0)                                              \
    __builtin_amdgcn_s_setprio(1);                                            \
    _Pragma("unroll")                                                         \
    for (int i = 0; i < MFR; ++i) {                                           \
        _Pragma("unroll")                                                     \
        for (int j = 0; j < NH; ++j)                                          \
            acc[i][(J0) + j] = __builtin_amdgcn_mfma_f32_16x16x32_bf16(       \
                AARR[i], BARR[j], acc[i][(J0) + j], 0, 0, 0);                 \
    }                                                                         \
    __builtin_amdgcn_s_setprio(0);

#pragma unroll 2
    for (int c = 0; c < NT; ++c) {
        const int bb = c & 1;
        const u16* SA1 = lds + (bb * 2 + 1) * (BM * 32);
        const u16* SB0 = SBb + (bb * 2 + 0) * (BN * 32);
        const u16* SB1 = SBb + (bb * 2 + 1) * (BN * 32);
        const u16* SA0n = lds + ((bb ^ 1) * 2) * (BM * 32);
        const u16* SB0n = SBb + ((bb ^ 1) * 2) * (BN * 32);
        const bool stg1 = (c + 1 < NT);
        const bool stg2 = (c + 2 < NT);

        // ================= P0: computes kh0 of tile c =================
        if (stg1) {
            asm volatile("s_waitcnt vmcnt(%0)" :: "i"(LA) : "memory");  // fbA ready
            writeB(c + 1, 0, fbA);
        }
#pragma unroll
        for (int j = 0; j < NH; ++j)
            bhi[j] = *(const bf16x8*)(SB0 + (nbase + (NH + j) * 16) * 32 + bxor);
#pragma unroll
        for (int i = 0; i < MFR; ++i)
            aN[i] = *(const bf16x8*)(SA1 + (arow + i * 16) * 32 + axor);
#pragma unroll
        for (int j = 0; j < NH; ++j)
            bloB[j] = *(const bf16x8*)(SB1 + (nbase + j * 16) * 32 + bxor);
        if (stg1) { loadB(c + 1, 1, fbB); stageA(c + 1, 1); }
        __builtin_amdgcn_sched_barrier(0);
        if (stg1) asm volatile("s_waitcnt lgkmcnt(%0)" :: "i"(WR + RD) : "memory");
        else      asm volatile("s_waitcnt lgkmcnt(%0)" :: "i"(RD) : "memory");
        __builtin_amdgcn_sched_barrier(0);
        MFMA_SUB(aC, bloA, 0);
        __builtin_amdgcn_sched_barrier(0);
        asm volatile("s_waitcnt lgkmcnt(%0)" :: "i"(MID) : "memory");
        __builtin_amdgcn_sched_barrier(0);
        MFMA_SUB(aC, bhi, NH);
        __builtin_amdgcn_sched_barrier(0);
        if (stg1) asm volatile("s_waitcnt vmcnt(%0)" :: "i"(VEND) : "memory");
        else      asm volatile("s_waitcnt vmcnt(0)" ::: "memory");
        __builtin_amdgcn_s_barrier();
        __builtin_amdgcn_sched_barrier(0);

        // ================= P1: computes kh1 of tile c =================
        if (stg1) {
            asm volatile("s_waitcnt vmcnt(%0)" :: "i"(LA) : "memory");  // fbB ready
            writeB(c + 1, 1, fbB);
        }
#pragma unroll
        for (int j = 0; j < NH; ++j)
            bhi[j] = *(const bf16x8*)(SB1 + (nbase + (NH + j) * 16) * 32 + bxor);
        if (stg1) {
#pragma unroll
            for (int i = 0; i < MFR; ++i)
                aC[i] = *(const bf16x8*)(SA0n + (arow + i * 16) * 32 + axor);
#pragma unroll
            for (int j = 0; j < NH; ++j)
                bloA[j] = *(const bf16x8*)(SB0n + (nbase + j * 16) * 32 + bxor);
        }
        if (stg2) { loadB(c + 2, 0, fbA); stageA(c + 2, 0); }
        __builtin_amdgcn_sched_barrier(0);
        if (stg1) asm volatile("s_waitcnt lgkmcnt(%0)" :: "i"(WR + NH + MFR + NH) : "memory");
        else      asm volatile("s_waitcnt lgkmcnt(%0)" :: "i"(NH) : "memory");
        __builtin_amdgcn_sched_barrier(0);
        MFMA_SUB(aN, bloB, 0);
        __builtin_amdgcn_sched_barrier(0);
        if (stg1) asm volatile("s_waitcnt lgkmcnt(%0)" :: "i"(MID) : "memory");
        else      asm volatile("s_waitcnt lgkmcnt(0)" ::: "memory");
        __builtin_amdgcn_sched_barrier(0);
        MFMA_SUB(aN, bhi, NH);
        __builtin_amdgcn_sched_barrier(0);
        if (stg2) asm volatile("s_waitcnt vmcnt(%0)" :: "i"(VEND) : "memory");
        else      asm volatile("s_waitcnt vmcnt(0)" ::: "memory");
        __builtin_amdgcn_s_barrier();
        __builtin_amdgcn_sched_barrier(0);
    }
#undef MFMA_SUB

    // ---- epilogue: C/D layout col=lane&15, row=(lane>>4)*4+t ----
    const int mb = m0 + wm * 64, nb = n0 + wn * (BN / 2);
    if constexpr (EPI == 1) {
        u16* C = (u16*)Cv + (size_t)e * Mpe * N;
#pragma unroll
        for (int i = 0; i < MFR; ++i) {
#pragma unroll
            for (int j = 0; j < NFR; ++j) {
                int col = nb + j * 16 + lr;
                float bv = bias[col];
                int row = mb + i * 16 + lg * 4;
#pragma unroll
                for (int t = 0; t < 4; ++t) {
                    float v = acc[i][j][t] + bv;
                    C[(size_t)(row + t) * N + col] = f2bf(gelu_fast(v));
                }
            }
        }
    } else {
        float* C = (float*)Cv + (size_t)e * Mpe * N;
#pragma unroll
        for (int i = 0; i < MFR; ++i) {
#pragma unroll
            for (int j = 0; j < NFR; ++j) {
                int col = nb + j * 16 + lr;
                float bv = bias[col];
                int row = mb + i * 16 + lg * 4;
#pragma unroll
                for (int t = 0; t < 4; ++t)
                    C[(size_t)(row + t) * N + col] = acc[i][j][t] + bv;
            }
        }
    }
}

extern "C" void kernel_launch(void* const* d_in, const int* in_sizes, int n_in,
                              void* d_out, int out_size, void* d_ws, size_t ws_size,
                              hipStream_t stream) {
    const float* X  = (const float*)d_in[0];
    // d_in[1] = expertFrequency (int64) — static equal split, unused
    const float* w1 = (const float*)d_in[2];
    const float* b1 = (const float*)d_in[3];
    const float* w2 = (const float*)d_in[4];
    const float* b2 = (const float*)d_in[5];
    float* out = (float*)d_out;

    // workspace layout (bytes): Xbf [T*D*2] | H [T*F*2]
    const size_t XBF_B = (size_t)T_ * D_ * 2;       // 16 MiB
    const size_t H_B   = (size_t)T_ * F_ * 2;       // 64 MiB
    if (ws_size < XBF_B + H_B) return;              // guard (80 MiB needed)

    char* ws = (char*)d_ws;
    u16* Xbf = (u16*)ws;
    u16* H   = (u16*)(ws + XBF_B);

    // 1. X fp32 -> bf16
    cvt_x<<<dim3((T_ * D_) / 8 / 256), dim3(256), 0, stream>>>(X, Xbf);
    // 2. H = gelu(X @ W1 + b1), bf16   (BM=256, BN=256; 512 wgs; W1 native)
    gemm2pw<256, 1, 4, 16><<<dim3(512), dim3(512), 0, stream>>>(
        Xbf, w1, b1, H, T_ / E_, F_, D_);
    // 3. out = H @ W2 + b2, fp32       (BM=256, BN=128; 256 wgs; W2 native)
    gemm2pw<128, 0, 4, 8><<<dim3(256), dim3(512), 0, stream>>>(
        H, w2, b2, out, T_ / E_, D_, F_);
}